// Round 1
// baseline (452.589 us; speedup 1.0000x reference)
//
#include <hip/hip_runtime.h>
#include <hip/hip_bf16.h>
#include <cstdint>
#include <cstddef>

#define B_ 4
#define L_ 4096
#define D_ 1024
#define FF_ 2048
#define ROWS (B_ * L_)   // 16384
#define EPS_ 1e-5f
#define CG 64            // conv chunks
#define CC 64            // conv chunk length (L_/CG)

typedef __attribute__((ext_vector_type(8))) __bf16 bf16x8;
typedef __attribute__((ext_vector_type(4))) float f32x4;
typedef __attribute__((ext_vector_type(4))) unsigned short us4;

__device__ __forceinline__ float bf2f(unsigned short u) {
  union { unsigned int i; float f; } v; v.i = ((unsigned int)u) << 16; return v.f;
}
__device__ __forceinline__ unsigned short f2bf(float f) {
  union { float f; unsigned int i; } v; v.f = f;
  unsigned int r = v.i + 0x7fffu + ((v.i >> 16) & 1u);
  return (unsigned short)(r >> 16);
}

// ---------------- weight transpose + cast: in [K,N] f32 -> out [N,K] bf16 ----
__global__ __launch_bounds__(256) void transpose_cast(
    const float* __restrict__ in, unsigned short* __restrict__ out, int K, int N) {
  __shared__ float tb[32][33];
  int n0 = blockIdx.x * 32, k0 = blockIdx.y * 32;
  int tx = threadIdx.x & 31, ty = threadIdx.x >> 5;  // 32 x 8
#pragma unroll
  for (int i = 0; i < 4; ++i) {
    int k = ty + i * 8;
    tb[k][tx] = in[(size_t)(k0 + k) * N + n0 + tx];
  }
  __syncthreads();
#pragma unroll
  for (int i = 0; i < 4; ++i) {
    int n = ty + i * 8;
    out[(size_t)(n0 + n) * K + k0 + tx] = f2bf(tb[tx][n]);
  }
}

// ---------------- LN1: x -> xn bf16 (LayerNorm), xb bf16 (plain cast) --------
__global__ __launch_bounds__(256) void ln1_kernel(
    const float* __restrict__ x, const float* __restrict__ g, const float* __restrict__ b,
    unsigned short* __restrict__ xn, unsigned short* __restrict__ xb) {
  int row = blockIdx.x;
  int t = threadIdx.x;
  const float4* xr = (const float4*)(x + (size_t)row * D_);
  float4 v = xr[t];
  float s = v.x + v.y + v.z + v.w;
  float sq = v.x * v.x + v.y * v.y + v.z * v.z + v.w * v.w;
#pragma unroll
  for (int off = 32; off > 0; off >>= 1) {
    s += __shfl_down(s, off);
    sq += __shfl_down(sq, off);
  }
  __shared__ float ls[4], lq[4];
  int lane = t & 63, w = t >> 6;
  if (lane == 0) { ls[w] = s; lq[w] = sq; }
  __syncthreads();
  s = ls[0] + ls[1] + ls[2] + ls[3];
  sq = lq[0] + lq[1] + lq[2] + lq[3];
  float mean = s * (1.0f / D_);
  float var = sq * (1.0f / D_) - mean * mean;
  float rstd = rsqrtf(var + EPS_);
  float4 gv = ((const float4*)g)[t];
  float4 bv = ((const float4*)b)[t];
  us4 o, ob;
  o.x = f2bf((v.x - mean) * rstd * gv.x + bv.x);
  o.y = f2bf((v.y - mean) * rstd * gv.y + bv.y);
  o.z = f2bf((v.z - mean) * rstd * gv.z + bv.z);
  o.w = f2bf((v.w - mean) * rstd * gv.w + bv.w);
  ob.x = f2bf(v.x); ob.y = f2bf(v.y); ob.z = f2bf(v.z); ob.w = f2bf(v.w);
  ((us4*)(xn + (size_t)row * D_))[t] = o;
  ((us4*)(xb + (size_t)row * D_))[t] = ob;
}

// ---------------- conv pass 1: per-chunk local recurrence --------------------
__global__ __launch_bounds__(256) void conv_pass1(
    const unsigned short* __restrict__ xn, const float* __restrict__ ph_re,
    const float* __restrict__ ph_im, float2* __restrict__ rloc) {
  int d = blockIdx.x * 256 + threadIdx.x;
  int g = blockIdx.y, b = blockIdx.z;
  float re = ph_re[d], im = ph_im[d];
  float a = sqrtf(re * re + im * im);
  float sc = expf(-a) / a;
  float pr = re * sc, pi = im * sc;
  float rr = 0.f, ri = 0.f;
  const unsigned short* xp = xn + ((size_t)(b * L_ + g * CC)) * D_ + d;
#pragma unroll 8
  for (int l = 0; l < CC; ++l) {
    float xv = bf2f(xp[(size_t)l * D_]);
    float nr = pr * rr - pi * ri + xv;
    ri = pr * ri + pi * rr;
    rr = nr;
  }
  rloc[((size_t)(b * CG + g)) * D_ + d] = make_float2(rr, ri);
}

// ---------------- conv pass 2: scan over chunks (carry-in per chunk) ---------
__global__ __launch_bounds__(256) void conv_pass2(
    const float* __restrict__ ph_re, const float* __restrict__ ph_im,
    const float2* __restrict__ rloc, float2* __restrict__ carry) {
  int idx = blockIdx.x * 256 + threadIdx.x;  // 0..B*D-1
  int b = idx >> 10, d = idx & (D_ - 1);
  float re = ph_re[d], im = ph_im[d];
  float a = sqrtf(re * re + im * im);
  float th = atan2f(im, re);
  float rho = expf(-a * (float)CC);
  float ang = th * (float)CC;
  float pcr = rho * cosf(ang), pci = rho * sinf(ang);
  float cr = 0.f, ci = 0.f;
  for (int g = 0; g < CG; ++g) {
    size_t o = ((size_t)(b * CG + g)) * D_ + d;
    carry[o] = make_float2(cr, ci);
    float2 rl = rloc[o];
    float nr = pcr * cr - pci * ci + rl.x;
    ci = pcr * ci + pci * cr + rl.y;
    cr = nr;
  }
}

// ---------------- conv pass 3: outputs -------------------------------------
__global__ __launch_bounds__(256) void conv_pass3(
    const unsigned short* __restrict__ xn,
    const float* __restrict__ ph_re, const float* __restrict__ ph_im,
    const float* __restrict__ phi_re, const float* __restrict__ phi_im,
    const float* __restrict__ lci_re, const float* __restrict__ lci_im,
    const float2* __restrict__ carry, unsigned short* __restrict__ cout) {
  int d = blockIdx.x * 256 + threadIdx.x;
  int g = blockIdx.y, b = blockIdx.z;
  float re = ph_re[d], im = ph_im[d];
  float a = sqrtf(re * re + im * im);
  float sc = expf(-a) / a;
  float pr = re * sc, pi = im * sc;
  float th = atan2f(im, re);
  int l0 = g * CC;
  float rho = expf(-a * (float)(l0 + 1));
  float ang = th * (float)(l0 + 1);
  float prr = rho * cosf(ang), pri = rho * sinf(ang);
  float fr = phi_re[d], fi = phi_im[d];
  float qr = lci_re[d], qi = lci_im[d];
  float2 cv = carry[((size_t)(b * CG + g)) * D_ + d];
  float rr = cv.x, ri = cv.y;
  const unsigned short* xp = xn + ((size_t)(b * L_ + l0)) * D_ + d;
  unsigned short* cp = cout + ((size_t)(b * L_ + l0)) * D_ + d;
#pragma unroll 4
  for (int l = 0; l < CC; ++l) {
    float xv = bf2f(xp[(size_t)l * D_]);
    float nr = pr * rr - pi * ri + xv;
    ri = pr * ri + pi * rr;
    rr = nr;
    float outv = fr * rr - fi * ri + qr * prr - qi * pri;  // Re(phi*r + lci*p)
    cp[(size_t)l * D_] = f2bf(outv);
    float pn = pr * prr - pi * pri;
    pri = pr * pri + pi * prr;
    prr = pn;
  }
}

// ---------------- LN2: x2 = c*y + x (f32 -> out), x3 = LN(x2) bf16 ----------
__global__ __launch_bounds__(256) void ln2_kernel(
    const unsigned short* __restrict__ c, const unsigned short* __restrict__ y,
    const float* __restrict__ x, const float* __restrict__ g, const float* __restrict__ b,
    float* __restrict__ x2, unsigned short* __restrict__ x3) {
  int row = blockIdx.x;
  int t = threadIdx.x;
  size_t base = (size_t)row * D_;
  us4 cv = ((const us4*)(c + base))[t];
  us4 yv = ((const us4*)(y + base))[t];
  float4 xv = ((const float4*)(x + base))[t];
  float4 v;
  v.x = bf2f(cv.x) * bf2f(yv.x) + xv.x;
  v.y = bf2f(cv.y) * bf2f(yv.y) + xv.y;
  v.z = bf2f(cv.z) * bf2f(yv.z) + xv.z;
  v.w = bf2f(cv.w) * bf2f(yv.w) + xv.w;
  ((float4*)(x2 + base))[t] = v;
  float s = v.x + v.y + v.z + v.w;
  float sq = v.x * v.x + v.y * v.y + v.z * v.z + v.w * v.w;
#pragma unroll
  for (int off = 32; off > 0; off >>= 1) {
    s += __shfl_down(s, off);
    sq += __shfl_down(sq, off);
  }
  __shared__ float ls[4], lq[4];
  int lane = t & 63, w = t >> 6;
  if (lane == 0) { ls[w] = s; lq[w] = sq; }
  __syncthreads();
  s = ls[0] + ls[1] + ls[2] + ls[3];
  sq = lq[0] + lq[1] + lq[2] + lq[3];
  float mean = s * (1.0f / D_);
  float var = sq * (1.0f / D_) - mean * mean;
  float rstd = rsqrtf(var + EPS_);
  float4 gv = ((const float4*)g)[t];
  float4 bv = ((const float4*)b)[t];
  us4 o;
  o.x = f2bf((v.x - mean) * rstd * gv.x + bv.x);
  o.y = f2bf((v.y - mean) * rstd * gv.y + bv.y);
  o.z = f2bf((v.z - mean) * rstd * gv.z + bv.z);
  o.w = f2bf((v.w - mean) * rstd * gv.w + bv.w);
  ((us4*)(x3 + base))[t] = o;
}

// ---------------- GEMM: A[M,K] bf16 @ Bt[N,K] bf16 -> C [M,N] ---------------
__device__ __forceinline__ void gld_lds16(const unsigned short* gp, unsigned short* lp) {
  __builtin_amdgcn_global_load_lds(
      (const __attribute__((address_space(1))) unsigned int*)gp,
      (__attribute__((address_space(3))) unsigned int*)lp, 16, 0, 0);
}

template <int SILU, int RES, int OUT_BF16>
__global__ __launch_bounds__(256) void gemm_bt(
    const unsigned short* __restrict__ A, const unsigned short* __restrict__ Bt,
    const float* __restrict__ bias, const float* __restrict__ res,
    void* __restrict__ Cv, int M, int N, int K) {
  __shared__ unsigned short As[128 * 32];
  __shared__ unsigned short Bs[128 * 32];
  int bx = blockIdx.x;  // M / 128
  int by = blockIdx.y;  // N / 128
  int t = threadIdx.x;
  int lane = t & 63, w = t >> 6;
  int wr = (w >> 1) * 64, wc = (w & 1) * 64;
  int frr = lane & 15, kb = (lane >> 4) * 8;

  f32x4 acc[4][4] = {};

  const unsigned short* ga = A + (size_t)(bx * 128 + (t >> 2)) * K + (t & 3) * 8;
  const unsigned short* gb = Bt + (size_t)(by * 128 + (t >> 2)) * K + (t & 3) * 8;

  for (int k0 = 0; k0 < K; k0 += 32) {
    gld_lds16(ga + k0, &As[t * 8]);
    gld_lds16(ga + k0 + (size_t)64 * K, &As[2048 + t * 8]);
    gld_lds16(gb + k0, &Bs[t * 8]);
    gld_lds16(gb + k0 + (size_t)64 * K, &Bs[2048 + t * 8]);
    __syncthreads();
    bf16x8 af[4], bf[4];
#pragma unroll
    for (int m = 0; m < 4; ++m)
      af[m] = *(const bf16x8*)&As[(wr + m * 16 + frr) * 32 + kb];
#pragma unroll
    for (int n = 0; n < 4; ++n)
      bf[n] = *(const bf16x8*)&Bs[(wc + n * 16 + frr) * 32 + kb];
#pragma unroll
    for (int m = 0; m < 4; ++m)
#pragma unroll
      for (int n = 0; n < 4; ++n)
        acc[m][n] = __builtin_amdgcn_mfma_f32_16x16x32_bf16(af[m], bf[n], acc[m][n], 0, 0, 0);
    __syncthreads();
  }

#pragma unroll
  for (int m = 0; m < 4; ++m) {
#pragma unroll
    for (int n = 0; n < 4; ++n) {
#pragma unroll
      for (int r = 0; r < 4; ++r) {
        int row = bx * 128 + wr + m * 16 + (lane >> 4) * 4 + r;
        int col = by * 128 + wc + n * 16 + frr;
        float v = acc[m][n][r] + bias[col];
        if (SILU) v = v / (1.0f + __expf(-v));
        if (RES) v += res[(size_t)row * N + col];
        if (OUT_BF16)
          ((unsigned short*)Cv)[(size_t)row * N + col] = f2bf(v);
        else
          ((float*)Cv)[(size_t)row * N + col] = v;
      }
    }
  }
}

// ---------------------------------------------------------------------------
extern "C" void kernel_launch(void* const* d_in, const int* in_sizes, int n_in,
                              void* d_out, int out_size, void* d_ws, size_t ws_size,
                              hipStream_t stream) {
  const float* x      = (const float*)d_in[0];
  const float* ln_g   = (const float*)d_in[1];
  const float* ln_b   = (const float*)d_in[2];
  const float* fc_w   = (const float*)d_in[3];
  const float* fc_b   = (const float*)d_in[4];
  const float* w1     = (const float*)d_in[5];
  const float* b1     = (const float*)d_in[6];
  const float* w2     = (const float*)d_in[7];
  const float* b2     = (const float*)d_in[8];
  const float* ph_re  = (const float*)d_in[9];
  const float* ph_im  = (const float*)d_in[10];
  const float* phi_re = (const float*)d_in[11];
  const float* phi_im = (const float*)d_in[12];
  const float* lci_re = (const float*)d_in[13];
  const float* lci_im = (const float*)d_in[14];
  float* out = (float*)d_out;

  char* ws = (char*)d_ws;
  const size_t SZ_BF = (size_t)ROWS * D_ * 2;  // 33,554,432 bytes
  unsigned short* xn_y  = (unsigned short*)(ws);               // xn, then y (after conv)
  unsigned short* cbuf  = (unsigned short*)(ws + SZ_BF);       // conv output
  unsigned short* xb_x3 = (unsigned short*)(ws + 2 * SZ_BF);   // x bf16, then x3 (after gemm1)
  unsigned short* h1    = (unsigned short*)(ws + 3 * SZ_BF);   // [ROWS, FF] bf16 (2*SZ_BF)
  unsigned short* fc_wt = (unsigned short*)(ws + 5 * SZ_BF);
  unsigned short* w1t   = (unsigned short*)(ws + 5 * SZ_BF + (size_t)D_ * D_ * 2);
  unsigned short* w2t   = (unsigned short*)(ws + 5 * SZ_BF + (size_t)D_ * D_ * 2 + (size_t)D_ * FF_ * 2);
  float2* rloc  = (float2*)(ws + 5 * SZ_BF + (size_t)D_ * D_ * 2 + 2 * (size_t)D_ * FF_ * 2);
  float2* carry = rloc + (size_t)B_ * CG * D_;

  // weight prep (bf16, transposed to [N,K])
  transpose_cast<<<dim3(D_ / 32, D_ / 32), 256, 0, stream>>>(fc_w, fc_wt, D_, D_);
  transpose_cast<<<dim3(FF_ / 32, D_ / 32), 256, 0, stream>>>(w1, w1t, D_, FF_);
  transpose_cast<<<dim3(D_ / 32, FF_ / 32), 256, 0, stream>>>(w2, w2t, FF_, D_);

  // LN1 + cast
  ln1_kernel<<<ROWS, 256, 0, stream>>>(x, ln_g, ln_b, xn_y, xb_x3);

  // conv (chunked scan)
  conv_pass1<<<dim3(D_ / 256, CG, B_), 256, 0, stream>>>(xn_y, ph_re, ph_im, rloc);
  conv_pass2<<<dim3((B_ * D_) / 256), 256, 0, stream>>>(ph_re, ph_im, rloc, carry);
  conv_pass3<<<dim3(D_ / 256, CG, B_), 256, 0, stream>>>(xn_y, ph_re, ph_im, phi_re, phi_im,
                                                         lci_re, lci_im, carry, cbuf);

  // y = silu(x @ fc_w + fc_b)  (bf16 out, reuses xn region)
  gemm_bt<1, 0, 1><<<dim3(ROWS / 128, D_ / 128), 256, 0, stream>>>(
      xb_x3, fc_wt, fc_b, nullptr, xn_y, ROWS, D_, D_);

  // x2 = c*y + x (f32 -> d_out), x3 = LN(x2) (bf16, reuses xb region)
  ln2_kernel<<<ROWS, 256, 0, stream>>>(cbuf, xn_y, x, ln_g, ln_b, out, xb_x3);

  // h1 = silu(x3 @ w1 + b1)
  gemm_bt<1, 0, 1><<<dim3(ROWS / 128, FF_ / 128), 256, 0, stream>>>(
      xb_x3, w1t, b1, nullptr, h1, ROWS, FF_, D_);

  // out = x2 + h1 @ w2 + b2
  gemm_bt<0, 1, 0><<<dim3(ROWS / 128, D_ / 128), 256, 0, stream>>>(
      h1, w2t, b2, out, out, ROWS, D_, FF_);
}

// Round 2
// 432.707 us; speedup vs baseline: 1.0459x; 1.0459x over previous
//
#include <hip/hip_runtime.h>
#include <hip/hip_bf16.h>
#include <cstdint>
#include <cstddef>

#define B_ 4
#define L_ 4096
#define D_ 1024
#define FF_ 2048
#define ROWS (B_ * L_)   // 16384
#define EPS_ 1e-5f
#define CG 64            // conv chunks
#define CC 64            // conv chunk length (L_/CG)

typedef __attribute__((ext_vector_type(8))) __bf16 bf16x8;
typedef __attribute__((ext_vector_type(4))) float f32x4;
typedef __attribute__((ext_vector_type(4))) unsigned short us4;

__device__ __forceinline__ float bf2f(unsigned short u) {
  union { unsigned int i; float f; } v; v.i = ((unsigned int)u) << 16; return v.f;
}
__device__ __forceinline__ unsigned short f2bf(float f) {
  union { float f; unsigned int i; } v; v.f = f;
  unsigned int r = v.i + 0x7fffu + ((v.i >> 16) & 1u);
  return (unsigned short)(r >> 16);
}

// ---------------- weight transpose + cast: in [K,N] f32 -> out [N,K] bf16 ----
__global__ __launch_bounds__(256) void transpose_cast(
    const float* __restrict__ in, unsigned short* __restrict__ out, int K, int N) {
  __shared__ float tb[32][33];
  int n0 = blockIdx.x * 32, k0 = blockIdx.y * 32;
  int tx = threadIdx.x & 31, ty = threadIdx.x >> 5;  // 32 x 8
#pragma unroll
  for (int i = 0; i < 4; ++i) {
    int k = ty + i * 8;
    tb[k][tx] = in[(size_t)(k0 + k) * N + n0 + tx];
  }
  __syncthreads();
#pragma unroll
  for (int i = 0; i < 4; ++i) {
    int n = ty + i * 8;
    out[(size_t)(n0 + n) * K + k0 + tx] = f2bf(tb[tx][n]);
  }
}

// ---------------- LN1: x -> xn bf16 (LayerNorm), xb bf16 (plain cast) --------
__global__ __launch_bounds__(256) void ln1_kernel(
    const float* __restrict__ x, const float* __restrict__ g, const float* __restrict__ b,
    unsigned short* __restrict__ xn, unsigned short* __restrict__ xb) {
  int row = blockIdx.x;
  int t = threadIdx.x;
  const float4* xr = (const float4*)(x + (size_t)row * D_);
  float4 v = xr[t];
  float s = v.x + v.y + v.z + v.w;
  float sq = v.x * v.x + v.y * v.y + v.z * v.z + v.w * v.w;
#pragma unroll
  for (int off = 32; off > 0; off >>= 1) {
    s += __shfl_down(s, off);
    sq += __shfl_down(sq, off);
  }
  __shared__ float ls[4], lq[4];
  int lane = t & 63, w = t >> 6;
  if (lane == 0) { ls[w] = s; lq[w] = sq; }
  __syncthreads();
  s = ls[0] + ls[1] + ls[2] + ls[3];
  sq = lq[0] + lq[1] + lq[2] + lq[3];
  float mean = s * (1.0f / D_);
  float var = sq * (1.0f / D_) - mean * mean;
  float rstd = rsqrtf(var + EPS_);
  float4 gv = ((const float4*)g)[t];
  float4 bv = ((const float4*)b)[t];
  us4 o, ob;
  o.x = f2bf((v.x - mean) * rstd * gv.x + bv.x);
  o.y = f2bf((v.y - mean) * rstd * gv.y + bv.y);
  o.z = f2bf((v.z - mean) * rstd * gv.z + bv.z);
  o.w = f2bf((v.w - mean) * rstd * gv.w + bv.w);
  ob.x = f2bf(v.x); ob.y = f2bf(v.y); ob.z = f2bf(v.z); ob.w = f2bf(v.w);
  ((us4*)(xn + (size_t)row * D_))[t] = o;
  ((us4*)(xb + (size_t)row * D_))[t] = ob;
}

// ---------------- conv pass 1: per-chunk local recurrence --------------------
__global__ __launch_bounds__(256) void conv_pass1(
    const unsigned short* __restrict__ xn, const float* __restrict__ ph_re,
    const float* __restrict__ ph_im, float2* __restrict__ rloc) {
  int d = blockIdx.x * 256 + threadIdx.x;
  int g = blockIdx.y, b = blockIdx.z;
  float re = ph_re[d], im = ph_im[d];
  float a = sqrtf(re * re + im * im);
  float sc = expf(-a) / a;
  float pr = re * sc, pi = im * sc;
  float rr = 0.f, ri = 0.f;
  const unsigned short* xp = xn + ((size_t)(b * L_ + g * CC)) * D_ + d;
#pragma unroll 8
  for (int l = 0; l < CC; ++l) {
    float xv = bf2f(xp[(size_t)l * D_]);
    float nr = pr * rr - pi * ri + xv;
    ri = pr * ri + pi * rr;
    rr = nr;
  }
  rloc[((size_t)(b * CG + g)) * D_ + d] = make_float2(rr, ri);
}

// ---------------- conv pass 2: scan over chunks (carry-in per chunk) ---------
__global__ __launch_bounds__(256) void conv_pass2(
    const float* __restrict__ ph_re, const float* __restrict__ ph_im,
    const float2* __restrict__ rloc, float2* __restrict__ carry) {
  int idx = blockIdx.x * 256 + threadIdx.x;  // 0..B*D-1
  int b = idx >> 10, d = idx & (D_ - 1);
  float re = ph_re[d], im = ph_im[d];
  float a = sqrtf(re * re + im * im);
  float th = atan2f(im, re);
  float rho = expf(-a * (float)CC);
  float ang = th * (float)CC;
  float pcr = rho * cosf(ang), pci = rho * sinf(ang);
  float cr = 0.f, ci = 0.f;
  for (int g = 0; g < CG; ++g) {
    size_t o = ((size_t)(b * CG + g)) * D_ + d;
    carry[o] = make_float2(cr, ci);
    float2 rl = rloc[o];
    float nr = pcr * cr - pci * ci + rl.x;
    ci = pcr * ci + pci * cr + rl.y;
    cr = nr;
  }
}

// ---------------- conv pass 3: outputs -------------------------------------
__global__ __launch_bounds__(256) void conv_pass3(
    const unsigned short* __restrict__ xn,
    const float* __restrict__ ph_re, const float* __restrict__ ph_im,
    const float* __restrict__ phi_re, const float* __restrict__ phi_im,
    const float* __restrict__ lci_re, const float* __restrict__ lci_im,
    const float2* __restrict__ carry, unsigned short* __restrict__ cout) {
  int d = blockIdx.x * 256 + threadIdx.x;
  int g = blockIdx.y, b = blockIdx.z;
  float re = ph_re[d], im = ph_im[d];
  float a = sqrtf(re * re + im * im);
  float sc = expf(-a) / a;
  float pr = re * sc, pi = im * sc;
  float th = atan2f(im, re);
  int l0 = g * CC;
  float rho = expf(-a * (float)(l0 + 1));
  float ang = th * (float)(l0 + 1);
  float prr = rho * cosf(ang), pri = rho * sinf(ang);
  float fr = phi_re[d], fi = phi_im[d];
  float qr = lci_re[d], qi = lci_im[d];
  float2 cv = carry[((size_t)(b * CG + g)) * D_ + d];
  float rr = cv.x, ri = cv.y;
  const unsigned short* xp = xn + ((size_t)(b * L_ + l0)) * D_ + d;
  unsigned short* cp = cout + ((size_t)(b * L_ + l0)) * D_ + d;
#pragma unroll 4
  for (int l = 0; l < CC; ++l) {
    float xv = bf2f(xp[(size_t)l * D_]);
    float nr = pr * rr - pi * ri + xv;
    ri = pr * ri + pi * rr;
    rr = nr;
    float outv = fr * rr - fi * ri + qr * prr - qi * pri;  // Re(phi*r + lci*p)
    cp[(size_t)l * D_] = f2bf(outv);
    float pn = pr * prr - pi * pri;
    pri = pr * pri + pi * prr;
    prr = pn;
  }
}

// ---------------- LN2: x2 = c*y + x (f32 -> out), x3 = LN(x2) bf16 ----------
__global__ __launch_bounds__(256) void ln2_kernel(
    const unsigned short* __restrict__ c, const unsigned short* __restrict__ y,
    const float* __restrict__ x, const float* __restrict__ g, const float* __restrict__ b,
    float* __restrict__ x2, unsigned short* __restrict__ x3) {
  int row = blockIdx.x;
  int t = threadIdx.x;
  size_t base = (size_t)row * D_;
  us4 cv = ((const us4*)(c + base))[t];
  us4 yv = ((const us4*)(y + base))[t];
  float4 xv = ((const float4*)(x + base))[t];
  float4 v;
  v.x = bf2f(cv.x) * bf2f(yv.x) + xv.x;
  v.y = bf2f(cv.y) * bf2f(yv.y) + xv.y;
  v.z = bf2f(cv.z) * bf2f(yv.z) + xv.z;
  v.w = bf2f(cv.w) * bf2f(yv.w) + xv.w;
  ((float4*)(x2 + base))[t] = v;
  float s = v.x + v.y + v.z + v.w;
  float sq = v.x * v.x + v.y * v.y + v.z * v.z + v.w * v.w;
#pragma unroll
  for (int off = 32; off > 0; off >>= 1) {
    s += __shfl_down(s, off);
    sq += __shfl_down(sq, off);
  }
  __shared__ float ls[4], lq[4];
  int lane = t & 63, w = t >> 6;
  if (lane == 0) { ls[w] = s; lq[w] = sq; }
  __syncthreads();
  s = ls[0] + ls[1] + ls[2] + ls[3];
  sq = lq[0] + lq[1] + lq[2] + lq[3];
  float mean = s * (1.0f / D_);
  float var = sq * (1.0f / D_) - mean * mean;
  float rstd = rsqrtf(var + EPS_);
  float4 gv = ((const float4*)g)[t];
  float4 bv = ((const float4*)b)[t];
  us4 o;
  o.x = f2bf((v.x - mean) * rstd * gv.x + bv.x);
  o.y = f2bf((v.y - mean) * rstd * gv.y + bv.y);
  o.z = f2bf((v.z - mean) * rstd * gv.z + bv.z);
  o.w = f2bf((v.w - mean) * rstd * gv.w + bv.w);
  ((us4*)(x3 + base))[t] = o;
}

// ============================================================================
// GEMM: A[M,K] bf16 @ Bt[N,K] bf16 -> C [M,N]
// BM=256, BN=128, BK=64. 512 threads = 8 waves (4M x 2N), per-wave 64x64 out.
// 3-slot LDS ring (144 KiB), prefetch distance 2 tiles, one vmcnt(6)+s_barrier
// per K-tile (no drains in main loop). XOR-swizzled LDS (chunk ^= row&7) with
// pre-swizzled global source so global_load_lds dest stays linear.
// ============================================================================
__device__ __forceinline__ void gld_lds16(const unsigned short* gp, unsigned short* lp) {
  __builtin_amdgcn_global_load_lds(
      (const __attribute__((address_space(1))) unsigned int*)gp,
      (__attribute__((address_space(3))) unsigned int*)lp, 16, 0, 0);
}

template <int SILU, int RES, int OUT_BF16>
__global__ __launch_bounds__(512) void gemm_bt(
    const unsigned short* __restrict__ A, const unsigned short* __restrict__ Bt,
    const float* __restrict__ bias, const float* __restrict__ res,
    void* __restrict__ Cv, int MB, int N, int K) {
  __shared__ unsigned short As[3][256 * 64];  // 3 x 32 KiB
  __shared__ unsigned short Bs[3][128 * 64];  // 3 x 16 KiB

  int nwg = gridDim.x;
  int id = blockIdx.x;
  // bijective XCD swizzle (nwg % 8 == 0): XCD k gets a contiguous id2 chunk
  int q = nwg >> 3;
  int id2 = (id & 7) * q + (id >> 3);
  int bmIdx = id2 % MB;        // M fastest -> blocks on one XCD share B-panel
  int bnIdx = id2 / MB;
  int bm0 = bmIdx * 256, bn0 = bnIdx * 128;

  int t = threadIdx.x;
  int lane = t & 63, w = t >> 6;
  int wr = w >> 1, wc = w & 1;          // 4 x 2 waves
  int frr = lane & 15, cl = lane >> 4;  // fragment row, k-chunk

  int nt = K >> 6;  // K-tiles of 64

  // staging source (pre-swizzled): thread t loads row tr (+c*64), chunk jx
  int tr = t >> 3;
  int jx = (t & 7) ^ (tr & 7);
  const unsigned short* pA = A + (size_t)(bm0 + tr) * K + jx * 8;
  const unsigned short* pB = Bt + (size_t)(bn0 + tr) * K + jx * 8;

  auto stage = [&](int kt2, int slot) {
    const unsigned short* pa = pA + (size_t)kt2 * 64;
    unsigned short* da = &As[slot][t * 8];
#pragma unroll
    for (int c = 0; c < 4; ++c)
      gld_lds16(pa + (size_t)c * 64 * K, da + c * 4096);
    const unsigned short* pb = pB + (size_t)kt2 * 64;
    unsigned short* db = &Bs[slot][t * 8];
#pragma unroll
    for (int c = 0; c < 2; ++c)
      gld_lds16(pb + (size_t)c * 64 * K, db + c * 4096);
  };

  f32x4 acc[4][4] = {};

  // prologue: stage tiles 0,1; wait for tile 0 (6 newest = tile 1 may fly)
  stage(0, 0);
  stage(1, 1);
  asm volatile("s_waitcnt vmcnt(6)\n\ts_barrier" ::: "memory");

  int rowA = wr * 64 + frr;  // + m*16
  int rowB = wc * 64 + frr;  // + n*16
  int fx = frr & 7;

  int s = 0, ss = 2;
  for (int kt = 0; kt < nt; ++kt) {
    if (kt + 2 < nt) {
      stage(kt + 2, ss);
      ss = (ss == 2) ? 0 : ss + 1;
    }
    const unsigned short* as = As[s];
    const unsigned short* bs = Bs[s];
#pragma unroll
    for (int ks = 0; ks < 2; ++ks) {
      int ko = ((ks * 4 + cl) ^ fx) * 8;  // swizzled k-chunk offset
      bf16x8 af[4], bfr[4];
#pragma unroll
      for (int m = 0; m < 4; ++m)
        af[m] = *(const bf16x8*)&as[(rowA + m * 16) * 64 + ko];
#pragma unroll
      for (int n = 0; n < 4; ++n)
        bfr[n] = *(const bf16x8*)&bs[(rowB + n * 16) * 64 + ko];
      __builtin_amdgcn_s_setprio(1);
#pragma unroll
      for (int m = 0; m < 4; ++m)
#pragma unroll
        for (int n = 0; n < 4; ++n)
          acc[m][n] = __builtin_amdgcn_mfma_f32_16x16x32_bf16(af[m], bfr[n], acc[m][n], 0, 0, 0);
      __builtin_amdgcn_s_setprio(0);
    }
    s = (s == 2) ? 0 : s + 1;
    if (kt + 1 < nt) {
      if (kt + 2 < nt) {
        asm volatile("s_waitcnt vmcnt(6)\n\ts_barrier" ::: "memory");
      } else {
        asm volatile("s_waitcnt vmcnt(0)\n\ts_barrier" ::: "memory");
      }
    }
  }

  // epilogue
#pragma unroll
  for (int m = 0; m < 4; ++m) {
#pragma unroll
    for (int n = 0; n < 4; ++n) {
#pragma unroll
      for (int r = 0; r < 4; ++r) {
        int row = bm0 + wr * 64 + m * 16 + cl * 4 + r;
        int col = bn0 + wc * 64 + n * 16 + frr;
        float v = acc[m][n][r] + bias[col];
        if (SILU) v = v / (1.0f + __expf(-v));
        if (RES) v += res[(size_t)row * N + col];
        if (OUT_BF16)
          ((unsigned short*)Cv)[(size_t)row * N + col] = f2bf(v);
        else
          ((float*)Cv)[(size_t)row * N + col] = v;
      }
    }
  }
}

// ---------------------------------------------------------------------------
extern "C" void kernel_launch(void* const* d_in, const int* in_sizes, int n_in,
                              void* d_out, int out_size, void* d_ws, size_t ws_size,
                              hipStream_t stream) {
  const float* x      = (const float*)d_in[0];
  const float* ln_g   = (const float*)d_in[1];
  const float* ln_b   = (const float*)d_in[2];
  const float* fc_w   = (const float*)d_in[3];
  const float* fc_b   = (const float*)d_in[4];
  const float* w1     = (const float*)d_in[5];
  const float* b1     = (const float*)d_in[6];
  const float* w2     = (const float*)d_in[7];
  const float* b2     = (const float*)d_in[8];
  const float* ph_re  = (const float*)d_in[9];
  const float* ph_im  = (const float*)d_in[10];
  const float* phi_re = (const float*)d_in[11];
  const float* phi_im = (const float*)d_in[12];
  const float* lci_re = (const float*)d_in[13];
  const float* lci_im = (const float*)d_in[14];
  float* out = (float*)d_out;

  char* ws = (char*)d_ws;
  const size_t SZ_BF = (size_t)ROWS * D_ * 2;  // 33,554,432 bytes
  unsigned short* xn_y  = (unsigned short*)(ws);               // xn, then y (after conv)
  unsigned short* cbuf  = (unsigned short*)(ws + SZ_BF);       // conv output
  unsigned short* xb_x3 = (unsigned short*)(ws + 2 * SZ_BF);   // x bf16, then x3 (after gemm1)
  unsigned short* h1    = (unsigned short*)(ws + 3 * SZ_BF);   // [ROWS, FF] bf16 (2*SZ_BF)
  unsigned short* fc_wt = (unsigned short*)(ws + 5 * SZ_BF);
  unsigned short* w1t   = (unsigned short*)(ws + 5 * SZ_BF + (size_t)D_ * D_ * 2);
  unsigned short* w2t   = (unsigned short*)(ws + 5 * SZ_BF + (size_t)D_ * D_ * 2 + (size_t)D_ * FF_ * 2);
  float2* rloc  = (float2*)(ws + 5 * SZ_BF + (size_t)D_ * D_ * 2 + 2 * (size_t)D_ * FF_ * 2);
  float2* carry = rloc + (size_t)B_ * CG * D_;

  // weight prep (bf16, transposed to [N,K])
  transpose_cast<<<dim3(D_ / 32, D_ / 32), 256, 0, stream>>>(fc_w, fc_wt, D_, D_);
  transpose_cast<<<dim3(FF_ / 32, D_ / 32), 256, 0, stream>>>(w1, w1t, D_, FF_);
  transpose_cast<<<dim3(D_ / 32, FF_ / 32), 256, 0, stream>>>(w2, w2t, FF_, D_);

  // LN1 + cast
  ln1_kernel<<<ROWS, 256, 0, stream>>>(x, ln_g, ln_b, xn_y, xb_x3);

  // conv (chunked scan)
  conv_pass1<<<dim3(D_ / 256, CG, B_), 256, 0, stream>>>(xn_y, ph_re, ph_im, rloc);
  conv_pass2<<<dim3((B_ * D_) / 256), 256, 0, stream>>>(ph_re, ph_im, rloc, carry);
  conv_pass3<<<dim3(D_ / 256, CG, B_), 256, 0, stream>>>(xn_y, ph_re, ph_im, phi_re, phi_im,
                                                         lci_re, lci_im, carry, cbuf);

  // y = silu(x @ fc_w + fc_b)  (bf16 out, reuses xn region)
  gemm_bt<1, 0, 1><<<(ROWS / 256) * (D_ / 128), 512, 0, stream>>>(
      xb_x3, fc_wt, fc_b, nullptr, xn_y, ROWS / 256, D_, D_);

  // x2 = c*y + x (f32 -> d_out), x3 = LN(x2) (bf16, reuses xb region)
  ln2_kernel<<<ROWS, 256, 0, stream>>>(cbuf, xn_y, x, ln_g, ln_b, out, xb_x3);

  // h1 = silu(x3 @ w1 + b1)
  gemm_bt<1, 0, 1><<<(ROWS / 256) * (FF_ / 128), 512, 0, stream>>>(
      xb_x3, w1t, b1, nullptr, h1, ROWS / 256, FF_, D_);

  // out = x2 + h1 @ w2 + b2
  gemm_bt<0, 1, 0><<<(ROWS / 256) * (D_ / 128), 512, 0, stream>>>(
      h1, w2t, b2, out, out, ROWS / 256, D_, FF_);
}

// Round 3
// 372.241 us; speedup vs baseline: 1.2158x; 1.1624x over previous
//
#include <hip/hip_runtime.h>
#include <hip/hip_bf16.h>
#include <cstdint>
#include <cstddef>

#define B_ 4
#define L_ 4096
#define D_ 1024
#define FF_ 2048
#define ROWS (B_ * L_)   // 16384
#define EPS_ 1e-5f
#define CG 64            // conv chunks
#define CC 64            // conv chunk length (L_/CG)

typedef __attribute__((ext_vector_type(8))) __bf16 bf16x8;
typedef __attribute__((ext_vector_type(4))) float f32x4;
typedef __attribute__((ext_vector_type(4))) unsigned short us4;

__device__ __forceinline__ float bf2f(unsigned short u) {
  union { unsigned int i; float f; } v; v.i = ((unsigned int)u) << 16; return v.f;
}
__device__ __forceinline__ unsigned short f2bf(float f) {
  union { float f; unsigned int i; } v; v.f = f;
  unsigned int r = v.i + 0x7fffu + ((v.i >> 16) & 1u);
  return (unsigned short)(r >> 16);
}

// ---------------- weight transpose + cast: in [K,N] f32 -> out [N,K] bf16 ----
__global__ __launch_bounds__(256) void transpose_cast(
    const float* __restrict__ in, unsigned short* __restrict__ out, int K, int N) {
  __shared__ float tb[32][33];
  int n0 = blockIdx.x * 32, k0 = blockIdx.y * 32;
  int tx = threadIdx.x & 31, ty = threadIdx.x >> 5;  // 32 x 8
#pragma unroll
  for (int i = 0; i < 4; ++i) {
    int k = ty + i * 8;
    tb[k][tx] = in[(size_t)(k0 + k) * N + n0 + tx];
  }
  __syncthreads();
#pragma unroll
  for (int i = 0; i < 4; ++i) {
    int n = ty + i * 8;
    out[(size_t)(n0 + n) * K + k0 + tx] = f2bf(tb[tx][n]);
  }
}

// ---------------- LN1: x -> xn bf16 (LayerNorm), xb bf16 (plain cast) --------
__global__ __launch_bounds__(256) void ln1_kernel(
    const float* __restrict__ x, const float* __restrict__ g, const float* __restrict__ b,
    unsigned short* __restrict__ xn, unsigned short* __restrict__ xb) {
  int row = blockIdx.x;
  int t = threadIdx.x;
  const float4* xr = (const float4*)(x + (size_t)row * D_);
  float4 v = xr[t];
  float s = v.x + v.y + v.z + v.w;
  float sq = v.x * v.x + v.y * v.y + v.z * v.z + v.w * v.w;
#pragma unroll
  for (int off = 32; off > 0; off >>= 1) {
    s += __shfl_down(s, off);
    sq += __shfl_down(sq, off);
  }
  __shared__ float ls[4], lq[4];
  int lane = t & 63, w = t >> 6;
  if (lane == 0) { ls[w] = s; lq[w] = sq; }
  __syncthreads();
  s = ls[0] + ls[1] + ls[2] + ls[3];
  sq = lq[0] + lq[1] + lq[2] + lq[3];
  float mean = s * (1.0f / D_);
  float var = sq * (1.0f / D_) - mean * mean;
  float rstd = rsqrtf(var + EPS_);
  float4 gv = ((const float4*)g)[t];
  float4 bv = ((const float4*)b)[t];
  us4 o, ob;
  o.x = f2bf((v.x - mean) * rstd * gv.x + bv.x);
  o.y = f2bf((v.y - mean) * rstd * gv.y + bv.y);
  o.z = f2bf((v.z - mean) * rstd * gv.z + bv.z);
  o.w = f2bf((v.w - mean) * rstd * gv.w + bv.w);
  ob.x = f2bf(v.x); ob.y = f2bf(v.y); ob.z = f2bf(v.z); ob.w = f2bf(v.w);
  ((us4*)(xn + (size_t)row * D_))[t] = o;
  ((us4*)(xb + (size_t)row * D_))[t] = ob;
}

// ---------------- conv pass 1: per-chunk local recurrence --------------------
__global__ __launch_bounds__(256) void conv_pass1(
    const unsigned short* __restrict__ xn, const float* __restrict__ ph_re,
    const float* __restrict__ ph_im, float2* __restrict__ rloc) {
  int d = blockIdx.x * 256 + threadIdx.x;
  int g = blockIdx.y, b = blockIdx.z;
  float re = ph_re[d], im = ph_im[d];
  float a = sqrtf(re * re + im * im);
  float sc = expf(-a) / a;
  float pr = re * sc, pi = im * sc;
  float rr = 0.f, ri = 0.f;
  const unsigned short* xp = xn + ((size_t)(b * L_ + g * CC)) * D_ + d;
#pragma unroll 8
  for (int l = 0; l < CC; ++l) {
    float xv = bf2f(xp[(size_t)l * D_]);
    float nr = pr * rr - pi * ri + xv;
    ri = pr * ri + pi * rr;
    rr = nr;
  }
  rloc[((size_t)(b * CG + g)) * D_ + d] = make_float2(rr, ri);
}

// ---------------- conv pass 2: scan over chunks (carry-in per chunk) ---------
__global__ __launch_bounds__(256) void conv_pass2(
    const float* __restrict__ ph_re, const float* __restrict__ ph_im,
    const float2* __restrict__ rloc, float2* __restrict__ carry) {
  int idx = blockIdx.x * 256 + threadIdx.x;  // 0..B*D-1
  int b = idx >> 10, d = idx & (D_ - 1);
  float re = ph_re[d], im = ph_im[d];
  float a = sqrtf(re * re + im * im);
  float th = atan2f(im, re);
  float rho = expf(-a * (float)CC);
  float ang = th * (float)CC;
  float pcr = rho * cosf(ang), pci = rho * sinf(ang);
  float cr = 0.f, ci = 0.f;
  for (int g = 0; g < CG; ++g) {
    size_t o = ((size_t)(b * CG + g)) * D_ + d;
    carry[o] = make_float2(cr, ci);
    float2 rl = rloc[o];
    float nr = pcr * cr - pci * ci + rl.x;
    ci = pcr * ci + pci * cr + rl.y;
    cr = nr;
  }
}

// ---------------- conv pass 3: outputs -------------------------------------
__global__ __launch_bounds__(256) void conv_pass3(
    const unsigned short* __restrict__ xn,
    const float* __restrict__ ph_re, const float* __restrict__ ph_im,
    const float* __restrict__ phi_re, const float* __restrict__ phi_im,
    const float* __restrict__ lci_re, const float* __restrict__ lci_im,
    const float2* __restrict__ carry, unsigned short* __restrict__ cout) {
  int d = blockIdx.x * 256 + threadIdx.x;
  int g = blockIdx.y, b = blockIdx.z;
  float re = ph_re[d], im = ph_im[d];
  float a = sqrtf(re * re + im * im);
  float sc = expf(-a) / a;
  float pr = re * sc, pi = im * sc;
  float th = atan2f(im, re);
  int l0 = g * CC;
  float rho = expf(-a * (float)(l0 + 1));
  float ang = th * (float)(l0 + 1);
  float prr = rho * cosf(ang), pri = rho * sinf(ang);
  float fr = phi_re[d], fi = phi_im[d];
  float qr = lci_re[d], qi = lci_im[d];
  float2 cv = carry[((size_t)(b * CG + g)) * D_ + d];
  float rr = cv.x, ri = cv.y;
  const unsigned short* xp = xn + ((size_t)(b * L_ + l0)) * D_ + d;
  unsigned short* cp = cout + ((size_t)(b * L_ + l0)) * D_ + d;
#pragma unroll 4
  for (int l = 0; l < CC; ++l) {
    float xv = bf2f(xp[(size_t)l * D_]);
    float nr = pr * rr - pi * ri + xv;
    ri = pr * ri + pi * rr;
    rr = nr;
    float outv = fr * rr - fi * ri + qr * prr - qi * pri;  // Re(phi*r + lci*p)
    cp[(size_t)l * D_] = f2bf(outv);
    float pn = pr * prr - pi * pri;
    pri = pr * pri + pi * prr;
    prr = pn;
  }
}

// ---------------- LN2b: x3 = LN(x2) bf16 (x2 already in d_out) --------------
__global__ __launch_bounds__(256) void ln2b_kernel(
    const float* __restrict__ x2, const float* __restrict__ g, const float* __restrict__ b,
    unsigned short* __restrict__ x3) {
  int row = blockIdx.x;
  int t = threadIdx.x;
  size_t base = (size_t)row * D_;
  float4 v = ((const float4*)(x2 + base))[t];
  float s = v.x + v.y + v.z + v.w;
  float sq = v.x * v.x + v.y * v.y + v.z * v.z + v.w * v.w;
#pragma unroll
  for (int off = 32; off > 0; off >>= 1) {
    s += __shfl_down(s, off);
    sq += __shfl_down(sq, off);
  }
  __shared__ float ls[4], lq[4];
  int lane = t & 63, w = t >> 6;
  if (lane == 0) { ls[w] = s; lq[w] = sq; }
  __syncthreads();
  s = ls[0] + ls[1] + ls[2] + ls[3];
  sq = lq[0] + lq[1] + lq[2] + lq[3];
  float mean = s * (1.0f / D_);
  float var = sq * (1.0f / D_) - mean * mean;
  float rstd = rsqrtf(var + EPS_);
  float4 gv = ((const float4*)g)[t];
  float4 bv = ((const float4*)b)[t];
  us4 o;
  o.x = f2bf((v.x - mean) * rstd * gv.x + bv.x);
  o.y = f2bf((v.y - mean) * rstd * gv.y + bv.y);
  o.z = f2bf((v.z - mean) * rstd * gv.z + bv.z);
  o.w = f2bf((v.w - mean) * rstd * gv.w + bv.w);
  ((us4*)(x3 + base))[t] = o;
}

// ============================================================================
// GEMM: A[M,K] bf16 @ Bt[N,K] bf16 -> C [M,N]
// BM=256, BN=128, BK=64. 512 threads = 8 waves (4M x 2N), per-wave 64x64 out.
// 3-slot LDS ring, 2 phases per K-tile of 16 MFMA each:
//   {8 ds_read || 3 global_load_lds -> s_barrier -> lgkmcnt(0) -> 16 MFMA -> s_barrier}
// vmcnt(6) once per K-tile (tile kt+1 guaranteed landed, issued 2 phases ago).
// XOR-swizzled LDS (chunk ^= row&7), pre-swizzled global source.
// ============================================================================
__device__ __forceinline__ void gld_lds16(const unsigned short* gp, unsigned short* lp) {
  __builtin_amdgcn_global_load_lds(
      (const __attribute__((address_space(1))) unsigned int*)gp,
      (__attribute__((address_space(3))) unsigned int*)lp, 16, 0, 0);
}

template <int SILU, int RES, int OUT_BF16, int GATE>
__global__ __launch_bounds__(512) void gemm_bt(
    const unsigned short* __restrict__ A, const unsigned short* __restrict__ Bt,
    const float* __restrict__ bias, const float* __restrict__ res,
    const unsigned short* __restrict__ gate, const float* __restrict__ xres,
    void* __restrict__ Cv, int MB, int N, int K) {
  __shared__ unsigned short As[3][256 * 64];  // 3 x 32 KiB
  __shared__ unsigned short Bs[3][128 * 64];  // 3 x 16 KiB

  int nwg = gridDim.x;
  int id = blockIdx.x;
  int q = nwg >> 3;
  int id2 = (id & 7) * q + (id >> 3);  // bijective XCD swizzle (nwg % 8 == 0)
  int bmIdx = id2 % MB;
  int bnIdx = id2 / MB;
  int bm0 = bmIdx * 256, bn0 = bnIdx * 128;

  int t = threadIdx.x;
  int lane = t & 63, w = t >> 6;
  int wr = w >> 1, wc = w & 1;          // 4M x 2N waves
  int frr = lane & 15, cl = lane >> 4;
  int fx = frr & 7;
  int rowA = wr * 64 + frr;
  int rowB = wc * 64 + frr;

  int nt = K >> 6;

  // staging source (pre-swizzled): thread t covers row tr of each 64-row chunk
  int tr = t >> 3;
  int jx = (t & 7) ^ (tr & 7);
  const unsigned short* pA = A + (size_t)(bm0 + tr) * K + jx * 8;
  const unsigned short* pB = Bt + (size_t)(bn0 + tr) * K + jx * 8;

  // stage half h (h=0,1) of K-tile kt2 into slot: A rows 128h..128h+127, B rows 64h..64h+63
  auto stageH = [&](int kt2, int slot, int h) {
#pragma unroll
    for (int c = 2 * h; c < 2 * h + 2; ++c)
      gld_lds16(pA + (size_t)kt2 * 64 + (size_t)c * 64 * K, &As[slot][c * 4096 + t * 8]);
    gld_lds16(pB + (size_t)kt2 * 64 + (size_t)h * 64 * K, &Bs[slot][h * 4096 + t * 8]);
  };

  f32x4 acc[4][4] = {};

  // prologue: stage tiles 0,1 fully; wait tile 0 (6 newest = tile 1 in flight)
  stageH(0, 0, 0); stageH(0, 0, 1);
  stageH(1, 1, 0); stageH(1, 1, 1);
  asm volatile("s_waitcnt vmcnt(6)" ::: "memory");
  __builtin_amdgcn_s_barrier();

  int s = 0;
  for (int kt = 0; kt < nt; ++kt) {
    const unsigned short* as = As[s];
    const unsigned short* bs = Bs[s];
    int s2 = s + 2; if (s2 >= 3) s2 -= 3;
    // -------- phase 0 (ks = 0) --------
    bf16x8 a0[4], b0[4];
    int ko0 = (cl ^ fx) * 8;
#pragma unroll
    for (int m = 0; m < 4; ++m) a0[m] = *(const bf16x8*)&as[(rowA + m * 16) * 64 + ko0];
#pragma unroll
    for (int n = 0; n < 4; ++n) b0[n] = *(const bf16x8*)&bs[(rowB + n * 16) * 64 + ko0];
    if (kt + 2 < nt) stageH(kt + 2, s2, 0);
    __builtin_amdgcn_s_barrier();
    asm volatile("s_waitcnt lgkmcnt(0)" ::: "memory");
    __builtin_amdgcn_sched_barrier(0);
    __builtin_amdgcn_s_setprio(1);
#pragma unroll
    for (int m = 0; m < 4; ++m)
#pragma unroll
      for (int n = 0; n < 4; ++n)
        acc[m][n] = __builtin_amdgcn_mfma_f32_16x16x32_bf16(a0[m], b0[n], acc[m][n], 0, 0, 0);
    __builtin_amdgcn_s_setprio(0);
    __builtin_amdgcn_s_barrier();
    // -------- phase 1 (ks = 1) --------
    bf16x8 a1[4], b1[4];
    int ko1 = ((4 + cl) ^ fx) * 8;
#pragma unroll
    for (int m = 0; m < 4; ++m) a1[m] = *(const bf16x8*)&as[(rowA + m * 16) * 64 + ko1];
#pragma unroll
    for (int n = 0; n < 4; ++n) b1[n] = *(const bf16x8*)&bs[(rowB + n * 16) * 64 + ko1];
    if (kt + 2 < nt) {
      stageH(kt + 2, s2, 1);
      asm volatile("s_waitcnt vmcnt(6)" ::: "memory");  // tile kt+1 landed
    } else {
      asm volatile("s_waitcnt vmcnt(0)" ::: "memory");  // tail only
    }
    __builtin_amdgcn_s_barrier();
    asm volatile("s_waitcnt lgkmcnt(0)" ::: "memory");
    __builtin_amdgcn_sched_barrier(0);
    __builtin_amdgcn_s_setprio(1);
#pragma unroll
    for (int m = 0; m < 4; ++m)
#pragma unroll
      for (int n = 0; n < 4; ++n)
        acc[m][n] = __builtin_amdgcn_mfma_f32_16x16x32_bf16(a1[m], b1[n], acc[m][n], 0, 0, 0);
    __builtin_amdgcn_s_setprio(0);
    __builtin_amdgcn_s_barrier();
    s += 1; if (s == 3) s = 0;
  }

  // epilogue
#pragma unroll
  for (int m = 0; m < 4; ++m) {
#pragma unroll
    for (int n = 0; n < 4; ++n) {
#pragma unroll
      for (int r = 0; r < 4; ++r) {
        int row = bm0 + wr * 64 + m * 16 + cl * 4 + r;
        int col = bn0 + wc * 64 + n * 16 + frr;
        size_t o = (size_t)row * N + col;
        float v = acc[m][n][r] + bias[col];
        if (SILU) v = v / (1.0f + __expf(-v));
        if (GATE) v = bf2f(gate[o]) * v + xres[o];
        if (RES) v += res[o];
        if (OUT_BF16)
          ((unsigned short*)Cv)[o] = f2bf(v);
        else
          ((float*)Cv)[o] = v;
      }
    }
  }
}

// ---------------------------------------------------------------------------
extern "C" void kernel_launch(void* const* d_in, const int* in_sizes, int n_in,
                              void* d_out, int out_size, void* d_ws, size_t ws_size,
                              hipStream_t stream) {
  const float* x      = (const float*)d_in[0];
  const float* ln_g   = (const float*)d_in[1];
  const float* ln_b   = (const float*)d_in[2];
  const float* fc_w   = (const float*)d_in[3];
  const float* fc_b   = (const float*)d_in[4];
  const float* w1     = (const float*)d_in[5];
  const float* b1     = (const float*)d_in[6];
  const float* w2     = (const float*)d_in[7];
  const float* b2     = (const float*)d_in[8];
  const float* ph_re  = (const float*)d_in[9];
  const float* ph_im  = (const float*)d_in[10];
  const float* phi_re = (const float*)d_in[11];
  const float* phi_im = (const float*)d_in[12];
  const float* lci_re = (const float*)d_in[13];
  const float* lci_im = (const float*)d_in[14];
  float* out = (float*)d_out;

  char* ws = (char*)d_ws;
  const size_t SZ_BF = (size_t)ROWS * D_ * 2;  // 33,554,432 bytes
  unsigned short* xn    = (unsigned short*)(ws);               // LN1 out (conv input)
  unsigned short* cbuf  = (unsigned short*)(ws + SZ_BF);       // conv output
  unsigned short* xb_x3 = (unsigned short*)(ws + 2 * SZ_BF);   // x bf16, then x3 (after gemm1)
  unsigned short* h1    = (unsigned short*)(ws + 3 * SZ_BF);   // [ROWS, FF] bf16 (2*SZ_BF)
  unsigned short* fc_wt = (unsigned short*)(ws + 5 * SZ_BF);
  unsigned short* w1t   = (unsigned short*)(ws + 5 * SZ_BF + (size_t)D_ * D_ * 2);
  unsigned short* w2t   = (unsigned short*)(ws + 5 * SZ_BF + (size_t)D_ * D_ * 2 + (size_t)D_ * FF_ * 2);
  float2* rloc  = (float2*)(ws + 5 * SZ_BF + (size_t)D_ * D_ * 2 + 2 * (size_t)D_ * FF_ * 2);
  float2* carry = rloc + (size_t)B_ * CG * D_;

  // weight prep (bf16, transposed to [N,K])
  transpose_cast<<<dim3(D_ / 32, D_ / 32), 256, 0, stream>>>(fc_w, fc_wt, D_, D_);
  transpose_cast<<<dim3(FF_ / 32, D_ / 32), 256, 0, stream>>>(w1, w1t, D_, FF_);
  transpose_cast<<<dim3(D_ / 32, FF_ / 32), 256, 0, stream>>>(w2, w2t, FF_, D_);

  // LN1 + cast
  ln1_kernel<<<ROWS, 256, 0, stream>>>(x, ln_g, ln_b, xn, xb_x3);

  // conv (chunked scan)
  conv_pass1<<<dim3(D_ / 256, CG, B_), 256, 0, stream>>>(xn, ph_re, ph_im, rloc);
  conv_pass2<<<dim3((B_ * D_) / 256), 256, 0, stream>>>(ph_re, ph_im, rloc, carry);
  conv_pass3<<<dim3(D_ / 256, CG, B_), 256, 0, stream>>>(xn, ph_re, ph_im, phi_re, phi_im,
                                                         lci_re, lci_im, carry, cbuf);

  // x2 = c * silu(x @ fc_w + fc_b) + x  (fused gate, f32 -> d_out)
  gemm_bt<1, 0, 0, 1><<<(ROWS / 256) * (D_ / 128), 512, 0, stream>>>(
      xb_x3, fc_wt, fc_b, nullptr, cbuf, x, out, ROWS / 256, D_, D_);

  // x3 = LN(x2) (bf16, reuses xb region)
  ln2b_kernel<<<ROWS, 256, 0, stream>>>(out, ln_g, ln_b, xb_x3);

  // h1 = silu(x3 @ w1 + b1)
  gemm_bt<1, 0, 1, 0><<<(ROWS / 256) * (FF_ / 128), 512, 0, stream>>>(
      xb_x3, w1t, b1, nullptr, nullptr, nullptr, h1, ROWS / 256, FF_, D_);

  // out = x2 + h1 @ w2 + b2   (in-place residual from d_out)
  gemm_bt<0, 1, 0, 0><<<(ROWS / 256) * (D_ / 128), 512, 0, stream>>>(
      h1, w2t, b2, out, nullptr, nullptr, out, ROWS / 256, D_, FF_);
}

// Round 4
// 317.588 us; speedup vs baseline: 1.4251x; 1.1721x over previous
//
#include <hip/hip_runtime.h>
#include <hip/hip_bf16.h>
#include <cstdint>
#include <cstddef>

#define B_ 4
#define L_ 4096
#define D_ 1024
#define FF_ 2048
#define ROWS (B_ * L_)   // 16384
#define EPS_ 1e-5f
#define CG 64            // conv chunks
#define CC 64            // conv chunk length (L_/CG)

typedef __attribute__((ext_vector_type(8))) __bf16 bf16x8;
typedef __attribute__((ext_vector_type(4))) float f32x4;
typedef __attribute__((ext_vector_type(4))) unsigned short us4;

__device__ __forceinline__ float bf2f(unsigned short u) {
  union { unsigned int i; float f; } v; v.i = ((unsigned int)u) << 16; return v.f;
}
__device__ __forceinline__ unsigned short f2bf(float f) {
  union { float f; unsigned int i; } v; v.f = f;
  unsigned int r = v.i + 0x7fffu + ((v.i >> 16) & 1u);
  return (unsigned short)(r >> 16);
}

// ---------------- weight transpose + cast: in [K,N] f32 -> out [N,K] bf16 ----
__global__ __launch_bounds__(256) void transpose_cast(
    const float* __restrict__ in, unsigned short* __restrict__ out, int K, int N) {
  __shared__ float tb[32][33];
  int n0 = blockIdx.x * 32, k0 = blockIdx.y * 32;
  int tx = threadIdx.x & 31, ty = threadIdx.x >> 5;  // 32 x 8
#pragma unroll
  for (int i = 0; i < 4; ++i) {
    int k = ty + i * 8;
    tb[k][tx] = in[(size_t)(k0 + k) * N + n0 + tx];
  }
  __syncthreads();
#pragma unroll
  for (int i = 0; i < 4; ++i) {
    int n = ty + i * 8;
    out[(size_t)(n0 + n) * K + k0 + tx] = f2bf(tb[tx][n]);
  }
}

// ---------------- LN1: x -> xn bf16 (LayerNorm), xb bf16 (plain cast) --------
__global__ __launch_bounds__(256) void ln1_kernel(
    const float* __restrict__ x, const float* __restrict__ g, const float* __restrict__ b,
    unsigned short* __restrict__ xn, unsigned short* __restrict__ xb) {
  int row = blockIdx.x;
  int t = threadIdx.x;
  const float4* xr = (const float4*)(x + (size_t)row * D_);
  float4 v = xr[t];
  float s = v.x + v.y + v.z + v.w;
  float sq = v.x * v.x + v.y * v.y + v.z * v.z + v.w * v.w;
#pragma unroll
  for (int off = 32; off > 0; off >>= 1) {
    s += __shfl_down(s, off);
    sq += __shfl_down(sq, off);
  }
  __shared__ float ls[4], lq[4];
  int lane = t & 63, w = t >> 6;
  if (lane == 0) { ls[w] = s; lq[w] = sq; }
  __syncthreads();
  s = ls[0] + ls[1] + ls[2] + ls[3];
  sq = lq[0] + lq[1] + lq[2] + lq[3];
  float mean = s * (1.0f / D_);
  float var = sq * (1.0f / D_) - mean * mean;
  float rstd = rsqrtf(var + EPS_);
  float4 gv = ((const float4*)g)[t];
  float4 bv = ((const float4*)b)[t];
  us4 o, ob;
  o.x = f2bf((v.x - mean) * rstd * gv.x + bv.x);
  o.y = f2bf((v.y - mean) * rstd * gv.y + bv.y);
  o.z = f2bf((v.z - mean) * rstd * gv.z + bv.z);
  o.w = f2bf((v.w - mean) * rstd * gv.w + bv.w);
  ob.x = f2bf(v.x); ob.y = f2bf(v.y); ob.z = f2bf(v.z); ob.w = f2bf(v.w);
  ((us4*)(xn + (size_t)row * D_))[t] = o;
  ((us4*)(xb + (size_t)row * D_))[t] = ob;
}

// ---------------- conv pass 1: per-chunk local recurrence --------------------
__global__ __launch_bounds__(256) void conv_pass1(
    const unsigned short* __restrict__ xn, const float* __restrict__ ph_re,
    const float* __restrict__ ph_im, float2* __restrict__ rloc) {
  int d = blockIdx.x * 256 + threadIdx.x;
  int g = blockIdx.y, b = blockIdx.z;
  float re = ph_re[d], im = ph_im[d];
  float a = sqrtf(re * re + im * im);
  float sc = expf(-a) / a;
  float pr = re * sc, pi = im * sc;
  float rr = 0.f, ri = 0.f;
  const unsigned short* xp = xn + ((size_t)(b * L_ + g * CC)) * D_ + d;
#pragma unroll 8
  for (int l = 0; l < CC; ++l) {
    float xv = bf2f(xp[(size_t)l * D_]);
    float nr = pr * rr - pi * ri + xv;
    ri = pr * ri + pi * rr;
    rr = nr;
  }
  rloc[((size_t)(b * CG + g)) * D_ + d] = make_float2(rr, ri);
}

// ---------------- conv pass 2: scan over chunks (carry-in per chunk) ---------
__global__ __launch_bounds__(256) void conv_pass2(
    const float* __restrict__ ph_re, const float* __restrict__ ph_im,
    const float2* __restrict__ rloc, float2* __restrict__ carry) {
  int idx = blockIdx.x * 256 + threadIdx.x;  // 0..B*D-1
  int b = idx >> 10, d = idx & (D_ - 1);
  float re = ph_re[d], im = ph_im[d];
  float a = sqrtf(re * re + im * im);
  float th = atan2f(im, re);
  float rho = expf(-a * (float)CC);
  float ang = th * (float)CC;
  float pcr = rho * cosf(ang), pci = rho * sinf(ang);
  float cr = 0.f, ci = 0.f;
  for (int g = 0; g < CG; ++g) {
    size_t o = ((size_t)(b * CG + g)) * D_ + d;
    carry[o] = make_float2(cr, ci);
    float2 rl = rloc[o];
    float nr = pcr * cr - pci * ci + rl.x;
    ci = pcr * ci + pci * cr + rl.y;
    cr = nr;
  }
}

// ---------------- conv pass 3: outputs -------------------------------------
__global__ __launch_bounds__(256) void conv_pass3(
    const unsigned short* __restrict__ xn,
    const float* __restrict__ ph_re, const float* __restrict__ ph_im,
    const float* __restrict__ phi_re, const float* __restrict__ phi_im,
    const float* __restrict__ lci_re, const float* __restrict__ lci_im,
    const float2* __restrict__ carry, unsigned short* __restrict__ cout) {
  int d = blockIdx.x * 256 + threadIdx.x;
  int g = blockIdx.y, b = blockIdx.z;
  float re = ph_re[d], im = ph_im[d];
  float a = sqrtf(re * re + im * im);
  float sc = expf(-a) / a;
  float pr = re * sc, pi = im * sc;
  float th = atan2f(im, re);
  int l0 = g * CC;
  float rho = expf(-a * (float)(l0 + 1));
  float ang = th * (float)(l0 + 1);
  float prr = rho * cosf(ang), pri = rho * sinf(ang);
  float fr = phi_re[d], fi = phi_im[d];
  float qr = lci_re[d], qi = lci_im[d];
  float2 cv = carry[((size_t)(b * CG + g)) * D_ + d];
  float rr = cv.x, ri = cv.y;
  const unsigned short* xp = xn + ((size_t)(b * L_ + l0)) * D_ + d;
  unsigned short* cp = cout + ((size_t)(b * L_ + l0)) * D_ + d;
#pragma unroll 4
  for (int l = 0; l < CC; ++l) {
    float xv = bf2f(xp[(size_t)l * D_]);
    float nr = pr * rr - pi * ri + xv;
    ri = pr * ri + pi * rr;
    rr = nr;
    float outv = fr * rr - fi * ri + qr * prr - qi * pri;  // Re(phi*r + lci*p)
    cp[(size_t)l * D_] = f2bf(outv);
    float pn = pr * prr - pi * pri;
    pri = pr * pri + pi * prr;
    prr = pn;
  }
}

// ---------------- LN2b: x3 = LN(x2) bf16 (x2 already in d_out) --------------
__global__ __launch_bounds__(256) void ln2b_kernel(
    const float* __restrict__ x2, const float* __restrict__ g, const float* __restrict__ b,
    unsigned short* __restrict__ x3) {
  int row = blockIdx.x;
  int t = threadIdx.x;
  size_t base = (size_t)row * D_;
  float4 v = ((const float4*)(x2 + base))[t];
  float s = v.x + v.y + v.z + v.w;
  float sq = v.x * v.x + v.y * v.y + v.z * v.z + v.w * v.w;
#pragma unroll
  for (int off = 32; off > 0; off >>= 1) {
    s += __shfl_down(s, off);
    sq += __shfl_down(sq, off);
  }
  __shared__ float ls[4], lq[4];
  int lane = t & 63, w = t >> 6;
  if (lane == 0) { ls[w] = s; lq[w] = sq; }
  __syncthreads();
  s = ls[0] + ls[1] + ls[2] + ls[3];
  sq = lq[0] + lq[1] + lq[2] + lq[3];
  float mean = s * (1.0f / D_);
  float var = sq * (1.0f / D_) - mean * mean;
  float rstd = rsqrtf(var + EPS_);
  float4 gv = ((const float4*)g)[t];
  float4 bv = ((const float4*)b)[t];
  us4 o;
  o.x = f2bf((v.x - mean) * rstd * gv.x + bv.x);
  o.y = f2bf((v.y - mean) * rstd * gv.y + bv.y);
  o.z = f2bf((v.z - mean) * rstd * gv.z + bv.z);
  o.w = f2bf((v.w - mean) * rstd * gv.w + bv.w);
  ((us4*)(x3 + base))[t] = o;
}

// ============================================================================
// GEMM: A[M,K] bf16 @ Bt[N,K] bf16 -> C [M,N]
// BM=256, BN=256, BK=64. 512 threads = 8 waves (2M x 4N), per-wave 128x64 out.
// LDS: A dbuf (2x32K) + B ring (3x32K) = 160 KiB.
// 4 phases per K-tile (ks,mh quadrants), 16 MFMA each; A staged distance-1
// (L2-hot via m-group ordering), B staged distance-2 with vmcnt(4) counted.
// XOR-swizzled LDS (chunk ^= row&7), pre-swizzled global source.
// L2-locality ordering: XCD-contiguous chunks; within XCD sweep GROUP m-rows
// x all n (m fastest) so working set = GROUP*Arow + Bpanel <= 4 MiB L2.
// ============================================================================
__device__ __forceinline__ void gld_lds16(const unsigned short* gp, unsigned short* lp) {
  __builtin_amdgcn_global_load_lds(
      (const __attribute__((address_space(1))) unsigned int*)gp,
      (__attribute__((address_space(3))) unsigned int*)lp, 16, 0, 0);
}

template <int SILU, int RES, int OUT_BF16, int GATE>
__global__ __launch_bounds__(512) void gemm_bt(
    const unsigned short* __restrict__ A, const unsigned short* __restrict__ Bt,
    const float* __restrict__ bias, const float* __restrict__ res,
    const unsigned short* __restrict__ gate, const float* __restrict__ xres,
    void* __restrict__ Cv, int NB, int GROUP, int N, int K) {
  __shared__ unsigned short As[2][256 * 64];  // 2 x 32 KiB
  __shared__ unsigned short Bs[3][256 * 64];  // 3 x 32 KiB

  int nwg = gridDim.x;
  int xcd = blockIdx.x & 7;
  int lo = blockIdx.x >> 3;
  int q = nwg >> 3;               // blocks per XCD
  int gsz = GROUP * NB;
  int g_ = lo / gsz, r_ = lo % gsz;
  int n_ = r_ / GROUP, ml = r_ - n_ * GROUP;
  int Mx = q / NB;                // m-rows per XCD
  int bm0 = (xcd * Mx + g_ * GROUP + ml) * 256;
  int bn0 = n_ * 256;

  int t = threadIdx.x;
  int lane = t & 63, w = t >> 6;
  int wr = w >> 2, wc = w & 3;          // 2M x 4N waves
  int frr = lane & 15, cl = lane >> 4;
  int fx = frr & 7;
  int rA0 = wr * 128 + frr;             // + mh*64 + mi*16
  int rB0 = wc * 64 + frr;              // + ni*16
  int ko0 = (cl ^ fx) * 8;              // ks=0 swizzled chunk
  int ko1 = ((4 + cl) ^ fx) * 8;        // ks=1

  int nt = K >> 6;

  // staging source (pre-swizzled): thread t covers row tr of each 64-row chunk
  int tr = t >> 3;
  int jx = (t & 7) ^ (tr & 7);
  const unsigned short* pA = A + (size_t)(bm0 + tr) * K + jx * 8;
  const unsigned short* pB = Bt + (size_t)(bn0 + tr) * K + jx * 8;

  auto stageA2 = [&](int kt2, int slot, int h) {  // half h: row-chunks 2h,2h+1
#pragma unroll
    for (int c = 2 * h; c < 2 * h + 2; ++c)
      gld_lds16(pA + (size_t)kt2 * 64 + (size_t)c * 64 * K, &As[slot][c * 4096 + t * 8]);
  };
  auto stageB2 = [&](int kt2, int slot, int h) {
#pragma unroll
    for (int c = 2 * h; c < 2 * h + 2; ++c)
      gld_lds16(pB + (size_t)kt2 * 64 + (size_t)c * 64 * K, &Bs[slot][c * 4096 + t * 8]);
  };

  f32x4 acc[8][4] = {};

  // prologue: A0, B0, B1 (12 loads); wait A0+B0 (B1's 4 stay in flight)
  stageA2(0, 0, 0); stageA2(0, 0, 1);
  stageB2(0, 0, 0); stageB2(0, 0, 1);
  stageB2(1, 1, 0); stageB2(1, 1, 1);
  asm volatile("s_waitcnt vmcnt(4)" ::: "memory");
  __builtin_amdgcn_s_barrier();

  int sa = 0;
  int sb = 0;
  for (int kt = 0; kt < nt; ++kt) {
    const unsigned short* as = As[sa];
    const unsigned short* bs = Bs[sb];
    int sbn = sb + 2; if (sbn >= 3) sbn -= 3;   // B slot for kt+2
    bool pfA = kt + 1 < nt;
    bool pfB = kt + 2 < nt;
    bf16x8 a[4], bk[4];

    // -------- phase 0: ks=0, mh=0 --------
#pragma unroll
    for (int i = 0; i < 4; ++i) a[i] = *(const bf16x8*)&as[(rA0 + i * 16) * 64 + ko0];
#pragma unroll
    for (int i = 0; i < 4; ++i) bk[i] = *(const bf16x8*)&bs[(rB0 + i * 16) * 64 + ko0];
    if (pfA) stageA2(kt + 1, sa ^ 1, 0);
    __builtin_amdgcn_s_barrier();
    asm volatile("s_waitcnt lgkmcnt(0)" ::: "memory");
    __builtin_amdgcn_sched_barrier(0);
    __builtin_amdgcn_s_setprio(1);
#pragma unroll
    for (int m = 0; m < 4; ++m)
#pragma unroll
      for (int n = 0; n < 4; ++n)
        acc[m][n] = __builtin_amdgcn_mfma_f32_16x16x32_bf16(a[m], bk[n], acc[m][n], 0, 0, 0);
    __builtin_amdgcn_s_setprio(0);
    __builtin_amdgcn_s_barrier();

    // -------- phase 1: ks=0, mh=1 --------
#pragma unroll
    for (int i = 0; i < 4; ++i) a[i] = *(const bf16x8*)&as[(rA0 + 64 + i * 16) * 64 + ko0];
    if (pfA) stageA2(kt + 1, sa ^ 1, 1);
    __builtin_amdgcn_s_barrier();
    asm volatile("s_waitcnt lgkmcnt(0)" ::: "memory");
    __builtin_amdgcn_sched_barrier(0);
    __builtin_amdgcn_s_setprio(1);
#pragma unroll
    for (int m = 0; m < 4; ++m)
#pragma unroll
      for (int n = 0; n < 4; ++n)
        acc[4 + m][n] = __builtin_amdgcn_mfma_f32_16x16x32_bf16(a[m], bk[n], acc[4 + m][n], 0, 0, 0);
    __builtin_amdgcn_s_setprio(0);
    __builtin_amdgcn_s_barrier();

    // -------- phase 2: ks=1, mh=0 --------
#pragma unroll
    for (int i = 0; i < 4; ++i) a[i] = *(const bf16x8*)&as[(rA0 + i * 16) * 64 + ko1];
#pragma unroll
    for (int i = 0; i < 4; ++i) bk[i] = *(const bf16x8*)&bs[(rB0 + i * 16) * 64 + ko1];
    if (pfB) stageB2(kt + 2, sbn, 0);
    __builtin_amdgcn_s_barrier();
    asm volatile("s_waitcnt lgkmcnt(0)" ::: "memory");
    __builtin_amdgcn_sched_barrier(0);
    __builtin_amdgcn_s_setprio(1);
#pragma unroll
    for (int m = 0; m < 4; ++m)
#pragma unroll
      for (int n = 0; n < 4; ++n)
        acc[m][n] = __builtin_amdgcn_mfma_f32_16x16x32_bf16(a[m], bk[n], acc[m][n], 0, 0, 0);
    __builtin_amdgcn_s_setprio(0);
    __builtin_amdgcn_s_barrier();

    // -------- phase 3: ks=1, mh=1 --------
#pragma unroll
    for (int i = 0; i < 4; ++i) a[i] = *(const bf16x8*)&as[(rA0 + 64 + i * 16) * 64 + ko1];
    if (pfB) stageB2(kt + 2, sbn, 1);
    if (pfB) {
      asm volatile("s_waitcnt vmcnt(4)" ::: "memory");  // A(kt+1), B(kt+1) landed
    } else if (pfA) {
      asm volatile("s_waitcnt vmcnt(0)" ::: "memory");  // tail drain
    }
    __builtin_amdgcn_s_barrier();
    asm volatile("s_waitcnt lgkmcnt(0)" ::: "memory");
    __builtin_amdgcn_sched_barrier(0);
    __builtin_amdgcn_s_setprio(1);
#pragma unroll
    for (int m = 0; m < 4; ++m)
#pragma unroll
      for (int n = 0; n < 4; ++n)
        acc[4 + m][n] = __builtin_amdgcn_mfma_f32_16x16x32_bf16(a[m], bk[n], acc[4 + m][n], 0, 0, 0);
    __builtin_amdgcn_s_setprio(0);
    __builtin_amdgcn_s_barrier();

    sa ^= 1;
    sb += 1; if (sb == 3) sb = 0;
  }

  // epilogue
#pragma unroll
  for (int m = 0; m < 8; ++m) {
#pragma unroll
    for (int n = 0; n < 4; ++n) {
#pragma unroll
      for (int r = 0; r < 4; ++r) {
        int row = bm0 + wr * 128 + m * 16 + cl * 4 + r;
        int col = bn0 + wc * 64 + n * 16 + frr;
        size_t o = (size_t)row * N + col;
        float v = acc[m][n][r] + bias[col];
        if (SILU) v = v / (1.0f + __expf(-v));
        if (GATE) v = bf2f(gate[o]) * v + xres[o];
        if (RES) v += res[o];
        if (OUT_BF16)
          ((unsigned short*)Cv)[o] = f2bf(v);
        else
          ((float*)Cv)[o] = v;
      }
    }
  }
}

// ---------------------------------------------------------------------------
extern "C" void kernel_launch(void* const* d_in, const int* in_sizes, int n_in,
                              void* d_out, int out_size, void* d_ws, size_t ws_size,
                              hipStream_t stream) {
  const float* x      = (const float*)d_in[0];
  const float* ln_g   = (const float*)d_in[1];
  const float* ln_b   = (const float*)d_in[2];
  const float* fc_w   = (const float*)d_in[3];
  const float* fc_b   = (const float*)d_in[4];
  const float* w1     = (const float*)d_in[5];
  const float* b1     = (const float*)d_in[6];
  const float* w2     = (const float*)d_in[7];
  const float* b2     = (const float*)d_in[8];
  const float* ph_re  = (const float*)d_in[9];
  const float* ph_im  = (const float*)d_in[10];
  const float* phi_re = (const float*)d_in[11];
  const float* phi_im = (const float*)d_in[12];
  const float* lci_re = (const float*)d_in[13];
  const float* lci_im = (const float*)d_in[14];
  float* out = (float*)d_out;

  char* ws = (char*)d_ws;
  const size_t SZ_BF = (size_t)ROWS * D_ * 2;  // 33,554,432 bytes
  unsigned short* xn    = (unsigned short*)(ws);               // LN1 out (conv input)
  unsigned short* cbuf  = (unsigned short*)(ws + SZ_BF);       // conv output
  unsigned short* xb_x3 = (unsigned short*)(ws + 2 * SZ_BF);   // x bf16, then x3 (after gemm1)
  unsigned short* h1    = (unsigned short*)(ws + 3 * SZ_BF);   // [ROWS, FF] bf16 (2*SZ_BF)
  unsigned short* fc_wt = (unsigned short*)(ws + 5 * SZ_BF);
  unsigned short* w1t   = (unsigned short*)(ws + 5 * SZ_BF + (size_t)D_ * D_ * 2);
  unsigned short* w2t   = (unsigned short*)(ws + 5 * SZ_BF + (size_t)D_ * D_ * 2 + (size_t)D_ * FF_ * 2);
  float2* rloc  = (float2*)(ws + 5 * SZ_BF + (size_t)D_ * D_ * 2 + 2 * (size_t)D_ * FF_ * 2);
  float2* carry = rloc + (size_t)B_ * CG * D_;

  // weight prep (bf16, transposed to [N,K])
  transpose_cast<<<dim3(D_ / 32, D_ / 32), 256, 0, stream>>>(fc_w, fc_wt, D_, D_);
  transpose_cast<<<dim3(FF_ / 32, D_ / 32), 256, 0, stream>>>(w1, w1t, D_, FF_);
  transpose_cast<<<dim3(D_ / 32, FF_ / 32), 256, 0, stream>>>(w2, w2t, FF_, D_);

  // LN1 + cast
  ln1_kernel<<<ROWS, 256, 0, stream>>>(x, ln_g, ln_b, xn, xb_x3);

  // conv (chunked scan)
  conv_pass1<<<dim3(D_ / 256, CG, B_), 256, 0, stream>>>(xn, ph_re, ph_im, rloc);
  conv_pass2<<<dim3((B_ * D_) / 256), 256, 0, stream>>>(ph_re, ph_im, rloc, carry);
  conv_pass3<<<dim3(D_ / 256, CG, B_), 256, 0, stream>>>(xn, ph_re, ph_im, phi_re, phi_im,
                                                         lci_re, lci_im, carry, cbuf);

  // x2 = c * silu(x @ fc_w + fc_b) + x  (fused gate, f32 -> d_out)
  gemm_bt<1, 0, 0, 1><<<(ROWS / 256) * (D_ / 256), 512, 0, stream>>>(
      xb_x3, fc_wt, fc_b, nullptr, cbuf, x, out, D_ / 256, 4, D_, D_);

  // x3 = LN(x2) (bf16, reuses xb region)
  ln2b_kernel<<<ROWS, 256, 0, stream>>>(out, ln_g, ln_b, xb_x3);

  // h1 = silu(x3 @ w1 + b1)
  gemm_bt<1, 0, 1, 0><<<(ROWS / 256) * (FF_ / 256), 512, 0, stream>>>(
      xb_x3, w1t, b1, nullptr, nullptr, nullptr, h1, FF_ / 256, 4, FF_, D_);

  // out = x2 + h1 @ w2 + b2   (in-place residual from d_out)
  gemm_bt<0, 1, 0, 0><<<(ROWS / 256) * (D_ / 256), 512, 0, stream>>>(
      h1, w2t, b2, out, nullptr, nullptr, out, D_ / 256, 2, D_, FF_);
}